// Round 1
// baseline (249.546 us; speedup 1.0000x reference)
//
#include <hip/hip_runtime.h>
#include <hip/hip_bf16.h>

typedef __attribute__((ext_vector_type(8))) short short8_t;
typedef __attribute__((ext_vector_type(4))) float f32x4_t;
using u16 = unsigned short;

constexpr int S_LEN = 2048;
constexpr int EMB   = 1024;
constexpr int NH    = 16;
constexpr int HD    = 64;
constexpr int BATCH = 2;
constexpr int MR    = BATCH * S_LEN;  // 4096 rows
constexpr int E3    = 3 * EMB;        // 3072 (QKV concat)

#define L2E 1.44269504f

__device__ __forceinline__ u16 f2bf(float f) {
  unsigned u = __builtin_bit_cast(unsigned, f);
  unsigned r = 0x7fffu + ((u >> 16) & 1u);
  return (u16)((u + r) >> 16);
}

__device__ __forceinline__ void gld16(const void* g, void* l) {
  __builtin_amdgcn_global_load_lds(
      (const __attribute__((address_space(1))) void*)g,
      (__attribute__((address_space(3))) void*)l, 16, 0, 0);
}

// ---------------- fp32 -> bf16 conversion (vectorized, optional scale) ------
__global__ void k_cvt(const float* __restrict__ in, u16* __restrict__ out,
                      int n4, float scale) {
  int i = blockIdx.x * 256 + threadIdx.x;
  if (i >= n4) return;
  float4 v = reinterpret_cast<const float4*>(in)[i];
  ushort4 o;
  o.x = f2bf(v.x * scale);
  o.y = f2bf(v.y * scale);
  o.z = f2bf(v.z * scale);
  o.w = f2bf(v.w * scale);
  reinterpret_cast<ushort4*>(out)[i] = o;
}

// ---------------- bf16 GEMM, B^T input (C = A @ B^T), 128x128 tile ---------
// A: (M,K) row-major bf16. Bw: (N,K) row-major bf16 (i.e. weights as stored).
// F32OUT: fp32 output + bias; else bf16 output.
template <bool F32OUT>
__global__ __launch_bounds__(256) void k_gemm_bt(
    const u16* __restrict__ A, const u16* __restrict__ Bw,
    void* __restrict__ Cv, const float* __restrict__ bias,
    int M, int N, int K) {
  __shared__ short As[128 * 32];
  __shared__ short Bs[128 * 32];
  const int t    = threadIdx.x;
  const int w    = t >> 6;
  const int ln15 = t & 15;
  const int lg   = (t >> 4) & 3;
  const int wr   = w >> 1, wc = w & 1;
  const int m0   = blockIdx.y * 128, n0 = blockIdx.x * 128;

  // staging: 128x32 tile, linear element order; thread t loads 8 contiguous
  // bf16 at tile-elem t*8 (chunk 0) and 2048 + t*8 (chunk 1).
  const int srow = t >> 2;        // 0..63
  const int scol = (t & 3) * 8;   // 0,8,16,24
  const u16* gA = A + (size_t)(m0 + srow) * K + scol;
  const u16* gB = Bw + (size_t)(n0 + srow) * K + scol;
  short* lA = As + w * 512;       // wave-uniform LDS base (lane adds 16B slot)
  short* lB = Bs + w * 512;

  f32x4_t acc[4][4] = {};

  for (int k0 = 0; k0 < K; k0 += 32) {
    gld16(gA + k0, lA);
    gld16(gA + (size_t)64 * K + k0, lA + 2048);
    gld16(gB + k0, lB);
    gld16(gB + (size_t)64 * K + k0, lB + 2048);
    __syncthreads();
    short8_t af[4], bf[4];
#pragma unroll
    for (int i = 0; i < 4; ++i) {
      af[i] = *reinterpret_cast<const short8_t*>(
          &As[(wr * 64 + i * 16 + ln15) * 32 + 8 * lg]);
      bf[i] = *reinterpret_cast<const short8_t*>(
          &Bs[(wc * 64 + i * 16 + ln15) * 32 + 8 * lg]);
    }
#pragma unroll
    for (int i = 0; i < 4; ++i)
#pragma unroll
      for (int j = 0; j < 4; ++j)
        acc[i][j] = __builtin_amdgcn_mfma_f32_16x16x32_bf16(
            af[i], bf[j], acc[i][j], 0, 0, 0);
    __syncthreads();
  }

  if (F32OUT) {
    float* C = reinterpret_cast<float*>(Cv);
#pragma unroll
    for (int i = 0; i < 4; ++i)
#pragma unroll
      for (int j = 0; j < 4; ++j) {
        const int col = n0 + wc * 64 + j * 16 + ln15;
        const float bv = bias ? bias[col] : 0.0f;
#pragma unroll
        for (int r = 0; r < 4; ++r) {
          const int row = m0 + wr * 64 + i * 16 + lg * 4 + r;
          C[(size_t)row * N + col] = acc[i][j][r] + bv;
        }
      }
  } else {
    u16* C = reinterpret_cast<u16*>(Cv);
#pragma unroll
    for (int i = 0; i < 4; ++i)
#pragma unroll
      for (int j = 0; j < 4; ++j) {
        const int col = n0 + wc * 64 + j * 16 + ln15;
#pragma unroll
        for (int r = 0; r < 4; ++r) {
          const int row = m0 + wr * 64 + i * 16 + lg * 4 + r;
          C[(size_t)row * N + col] = f2bf(acc[i][j][r]);
        }
      }
  }
}

// ---------------- causal flash attention ------------------------------------
// QKV: (MR, 3072) bf16, cols [0,1024)=Q (pre-scaled by 1/8), [1024,2048)=K,
// [2048,3072)=V. ctx: (MR, 1024) bf16.
// grid: (S/64, B*H). 4 waves/block, each wave owns 16 q rows; KV tiles of 64.
__global__ __launch_bounds__(256) void k_attn(const u16* __restrict__ QKV,
                                              u16* __restrict__ ctx) {
  __shared__ short Ks[64][80];       // K tile, row-major [kv][d], padded
  __shared__ short Vts[64][80];      // V tile transposed [d][kv], padded
  __shared__ short Pls[4][16][80];   // per-wave P bounce [q][kv], padded

  const int t    = threadIdx.x;
  const int w    = t >> 6;
  const int ln15 = t & 15;
  const int lg   = (t >> 4) & 3;
  const int qt   = blockIdx.x;
  const int bh   = blockIdx.y;
  const int b    = bh >> 4;          // NH = 16
  const int h    = bh & 15;

  const u16* Qh = QKV + (size_t)b * S_LEN * E3 + h * HD;   // +1024 => K, +2048 => V
  const int qrow = qt * 64 + w * 16;

  // Q fragments (16 q rows x 64 d), A-operand layout: m=ln15, k=8*lg+j
  short8_t qf[2];
  {
    const u16* qp = Qh + (size_t)(qrow + ln15) * E3;
    qf[0] = *reinterpret_cast<const short8_t*>(qp + 8 * lg);
    qf[1] = *reinterpret_cast<const short8_t*>(qp + 32 + 8 * lg);
  }

  f32x4_t o[4] = {};
  float mrow[4], lrow[4];
#pragma unroll
  for (int r = 0; r < 4; ++r) { mrow[r] = -3e38f; lrow[r] = 0.0f; }

  const int rS = t >> 3;         // staging row 0..31 (chunk adds 32)
  const int cS = (t & 7) * 8;    // staging col 0..56

  for (int kvt = 0; kvt <= qt; ++kvt) {
    const int kv0 = kvt * 64;
    __syncthreads();  // previous tile's LDS reads complete before overwrite
#pragma unroll
    for (int c = 0; c < 2; ++c) {
      const int kr = rS + c * 32;
      const u16* gk = Qh + 1024 + (size_t)(kv0 + kr) * E3 + cS;
      short8_t kvv = *reinterpret_cast<const short8_t*>(gk);
      *reinterpret_cast<short8_t*>(&Ks[kr][cS]) = kvv;
      const u16* gv = Qh + 2048 + (size_t)(kv0 + kr) * E3 + cS;
      short8_t vvv = *reinterpret_cast<const short8_t*>(gv);
#pragma unroll
      for (int j = 0; j < 8; ++j) Vts[cS + j][kr] = vvv[j];
    }
    __syncthreads();

    // ---- S = Q K^T (16q x 64kv), 4 kv-subtiles of 16 ----
    float s[4][4];
#pragma unroll
    for (int ks = 0; ks < 4; ++ks) {
      f32x4_t sc = {0.0f, 0.0f, 0.0f, 0.0f};
      short8_t kf0 = *reinterpret_cast<const short8_t*>(&Ks[ks * 16 + ln15][8 * lg]);
      short8_t kf1 = *reinterpret_cast<const short8_t*>(&Ks[ks * 16 + ln15][32 + 8 * lg]);
      sc = __builtin_amdgcn_mfma_f32_16x16x32_bf16(qf[0], kf0, sc, 0, 0, 0);
      sc = __builtin_amdgcn_mfma_f32_16x16x32_bf16(qf[1], kf1, sc, 0, 0, 0);
#pragma unroll
      for (int r = 0; r < 4; ++r) s[ks][r] = sc[r];
    }

    if (kvt == qt) {  // causal mask on diagonal tile only
#pragma unroll
      for (int ks = 0; ks < 4; ++ks) {
        const int kcol = kv0 + ks * 16 + ln15;
#pragma unroll
        for (int r = 0; r < 4; ++r) {
          const int qr = qrow + lg * 4 + r;
          if (kcol > qr) s[ks][r] = -3e38f;
        }
      }
    }

    // ---- online softmax (rows owned: lg*4+r; cols spread over 16 lanes) ----
    float p[4][4];
#pragma unroll
    for (int r = 0; r < 4; ++r) {
      float rm = fmaxf(fmaxf(s[0][r], s[1][r]), fmaxf(s[2][r], s[3][r]));
      rm = fmaxf(rm, __shfl_xor(rm, 1));
      rm = fmaxf(rm, __shfl_xor(rm, 2));
      rm = fmaxf(rm, __shfl_xor(rm, 4));
      rm = fmaxf(rm, __shfl_xor(rm, 8));
      const float nm = fmaxf(mrow[r], rm);
      const float sc_old = exp2f((mrow[r] - nm) * L2E);
      mrow[r] = nm;
      float rs = 0.0f;
#pragma unroll
      for (int ks = 0; ks < 4; ++ks) {
        const float pv = exp2f((s[ks][r] - nm) * L2E);
        p[ks][r] = pv;
        rs += pv;
      }
      rs += __shfl_xor(rs, 1);
      rs += __shfl_xor(rs, 2);
      rs += __shfl_xor(rs, 4);
      rs += __shfl_xor(rs, 8);
      lrow[r] = lrow[r] * sc_old + rs;
#pragma unroll
      for (int nt = 0; nt < 4; ++nt) o[nt][r] *= sc_old;
    }

    // ---- P -> per-wave LDS (bf16), then PV MFMA ----
#pragma unroll
    for (int ks = 0; ks < 4; ++ks)
#pragma unroll
      for (int r = 0; r < 4; ++r)
        Pls[w][lg * 4 + r][ks * 16 + ln15] = (short)f2bf(p[ks][r]);

#pragma unroll
    for (int hh = 0; hh < 2; ++hh) {
      short8_t pa = *reinterpret_cast<const short8_t*>(
          &Pls[w][ln15][hh * 32 + 8 * lg]);
#pragma unroll
      for (int nt = 0; nt < 4; ++nt) {
        short8_t vf = *reinterpret_cast<const short8_t*>(
            &Vts[nt * 16 + ln15][hh * 32 + 8 * lg]);
        o[nt] = __builtin_amdgcn_mfma_f32_16x16x32_bf16(pa, vf, o[nt], 0, 0, 0);
      }
    }
  }

  // ---- epilogue: normalize and write ctx ----
#pragma unroll
  for (int r = 0; r < 4; ++r) {
    const float inv = 1.0f / lrow[r];
    const int qr = qrow + lg * 4 + r;
    u16* op = ctx + (size_t)(b * S_LEN + qr) * EMB + h * HD;
#pragma unroll
    for (int nt = 0; nt < 4; ++nt)
      op[nt * 16 + ln15] = f2bf(o[nt][r] * inv);
  }
}

// ---------------------------------------------------------------------------
extern "C" void kernel_launch(void* const* d_in, const int* in_sizes, int n_in,
                              void* d_out, int out_size, void* d_ws, size_t ws_size,
                              hipStream_t stream) {
  const float* x  = (const float*)d_in[0];
  const float* Wq = (const float*)d_in[1];
  const float* Wk = (const float*)d_in[2];
  const float* Wv = (const float*)d_in[3];
  const float* Wo = (const float*)d_in[4];
  const float* bo = (const float*)d_in[5];

  u16* ws   = (u16*)d_ws;
  u16* xb   = ws;                               // 4096*1024
  u16* wcat = xb + (size_t)MR * EMB;            // 3*1024*1024 (Wq|Wk|Wv rows)
  u16* wob  = wcat + (size_t)3 * EMB * EMB;     // 1024*1024
  u16* qkv  = wob + (size_t)EMB * EMB;          // 4096*3072
  u16* ctxb = qkv + (size_t)MR * E3;            // 4096*1024
  // total ws use: ~48 MiB of bf16

  // fp32 -> bf16 (Wq folded with softmax scale 1/sqrt(64) = 0.125, exact)
  k_cvt<<<(MR * EMB / 4 + 255) / 256, 256, 0, stream>>>(x, xb, MR * EMB / 4, 1.0f);
  k_cvt<<<(EMB * EMB / 4 + 255) / 256, 256, 0, stream>>>(Wq, wcat, EMB * EMB / 4, 0.125f);
  k_cvt<<<(EMB * EMB / 4 + 255) / 256, 256, 0, stream>>>(Wk, wcat + (size_t)EMB * EMB, EMB * EMB / 4, 1.0f);
  k_cvt<<<(EMB * EMB / 4 + 255) / 256, 256, 0, stream>>>(Wv, wcat + (size_t)2 * EMB * EMB, EMB * EMB / 4, 1.0f);
  k_cvt<<<(EMB * EMB / 4 + 255) / 256, 256, 0, stream>>>(Wo, wob, EMB * EMB / 4, 1.0f);

  // QKV = x @ Wcat^T  (M=4096, N=3072, K=1024), bf16 out
  k_gemm_bt<false><<<dim3(E3 / 128, MR / 128), 256, 0, stream>>>(
      xb, wcat, qkv, nullptr, MR, E3, EMB);

  // causal flash attention -> ctx (bf16)
  k_attn<<<dim3(S_LEN / 64, BATCH * NH), 256, 0, stream>>>(qkv, ctxb);

  // out = ctx @ Wo^T + bo  (fp32 out)
  k_gemm_bt<true><<<dim3(EMB / 128, MR / 128), 256, 0, stream>>>(
      ctxb, wob, d_out, bo, MR, EMB, EMB);
}

// Round 3
// 127.857 us; speedup vs baseline: 1.9518x; 1.9518x over previous
//
#include <hip/hip_runtime.h>
#include <hip/hip_bf16.h>

typedef __attribute__((ext_vector_type(8))) short short8_t;
typedef __attribute__((ext_vector_type(4))) short s4v;
typedef __attribute__((ext_vector_type(4))) float f32x4_t;
using u16 = unsigned short;

constexpr int S_LEN = 2048;
constexpr int EMB   = 1024;
constexpr int NH    = 16;
constexpr int HD    = 64;
constexpr int BATCH = 2;
constexpr int MR    = BATCH * S_LEN;  // 4096
constexpr int E3    = 3 * EMB;        // 3072

#define L2E 1.44269504f

__device__ __forceinline__ u16 f2bf(float f) {
  unsigned u = __builtin_bit_cast(unsigned, f);
  unsigned r = 0x7fffu + ((u >> 16) & 1u);
  return (u16)((u + r) >> 16);
}

__device__ __forceinline__ void gld16(const void* g, void* l) {
  __builtin_amdgcn_global_load_lds(
      (const __attribute__((address_space(1))) void*)g,
      (__attribute__((address_space(3))) void*)l, 16, 0, 0);
}

// hardware transpose read. Canonical per-lane address = base + 8B*lane:
// lane l, elem j <- lds_elem[64*(l>>4) + 16*j + (l&15)] (+ offset/2 elems).
template <int OFF>
__device__ __forceinline__ s4v tr16(const __attribute__((address_space(3))) u16* p) {
  s4v d;
  asm volatile("ds_read_b64_tr_b16 %0, %1 offset:%2"
               : "=v"(d) : "v"(p), "n"(OFF));
  return d;
}

// ---------------- fused fp32 -> bf16 conversion ----------------------------
// dest layout (contiguous in ws): xb(4M) | Wq(1M,*0.125) | Wk | Wv | Wo
__global__ void k_cvt_all(const float* __restrict__ x, const float* __restrict__ Wq,
                          const float* __restrict__ Wk, const float* __restrict__ Wv,
                          const float* __restrict__ Wo, u16* __restrict__ out) {
  int i = blockIdx.x * 256 + threadIdx.x;  // float4 index, total 2M
  const float* src;
  int j;
  float sc = 1.0f;
  if (i < (1 << 20)) {
    src = x; j = i;
  } else {
    int jj = i - (1 << 20);
    int r = jj >> 18;
    j = jj & ((1 << 18) - 1);
    src = (r == 0) ? Wq : (r == 1) ? Wk : (r == 2) ? Wv : Wo;
    if (r == 0) sc = 0.125f;  // fold softmax 1/sqrt(64)
  }
  float4 v = reinterpret_cast<const float4*>(src)[j];
  ushort4 o;
  o.x = f2bf(v.x * sc); o.y = f2bf(v.y * sc);
  o.z = f2bf(v.z * sc); o.w = f2bf(v.w * sc);
  reinterpret_cast<ushort4*>(out)[i] = o;
}

// ---------------- bf16 GEMM, B^T input (C = A @ B^T), 128x128 tile ---------
template <bool F32OUT>
__global__ __launch_bounds__(256) void k_gemm_bt(
    const u16* __restrict__ A, const u16* __restrict__ Bw,
    void* __restrict__ Cv, const float* __restrict__ bias,
    int M, int N, int K) {
  __shared__ short As[128 * 32];
  __shared__ short Bs[128 * 32];
  const int t    = threadIdx.x;
  const int w    = t >> 6;
  const int ln15 = t & 15;
  const int lg   = (t >> 4) & 3;
  const int wr   = w >> 1, wc = w & 1;
  const int m0   = blockIdx.y * 128, n0 = blockIdx.x * 128;

  const int srow = t >> 2;
  const int scol = (t & 3) * 8;
  const u16* gA = A + (size_t)(m0 + srow) * K + scol;
  const u16* gB = Bw + (size_t)(n0 + srow) * K + scol;
  short* lA = As + w * 512;
  short* lB = Bs + w * 512;

  f32x4_t acc[4][4] = {};

  for (int k0 = 0; k0 < K; k0 += 32) {
    gld16(gA + k0, lA);
    gld16(gA + (size_t)64 * K + k0, lA + 2048);
    gld16(gB + k0, lB);
    gld16(gB + (size_t)64 * K + k0, lB + 2048);
    __syncthreads();
    short8_t af[4], bf[4];
#pragma unroll
    for (int i = 0; i < 4; ++i) {
      af[i] = *reinterpret_cast<const short8_t*>(
          &As[(wr * 64 + i * 16 + ln15) * 32 + 8 * lg]);
      bf[i] = *reinterpret_cast<const short8_t*>(
          &Bs[(wc * 64 + i * 16 + ln15) * 32 + 8 * lg]);
    }
#pragma unroll
    for (int i = 0; i < 4; ++i)
#pragma unroll
      for (int j = 0; j < 4; ++j)
        acc[i][j] = __builtin_amdgcn_mfma_f32_16x16x32_bf16(
            af[i], bf[j], acc[i][j], 0, 0, 0);
    __syncthreads();
  }

  if (F32OUT) {
    float* C = reinterpret_cast<float*>(Cv);
#pragma unroll
    for (int i = 0; i < 4; ++i)
#pragma unroll
      for (int j = 0; j < 4; ++j) {
        const int col = n0 + wc * 64 + j * 16 + ln15;
        const float bv = bias ? bias[col] : 0.0f;
#pragma unroll
        for (int r = 0; r < 4; ++r) {
          const int row = m0 + wr * 64 + i * 16 + lg * 4 + r;
          C[(size_t)row * N + col] = acc[i][j][r] + bv;
        }
      }
  } else {
    u16* C = reinterpret_cast<u16*>(Cv);
#pragma unroll
    for (int i = 0; i < 4; ++i)
#pragma unroll
      for (int j = 0; j < 4; ++j) {
        const int col = n0 + wc * 64 + j * 16 + ln15;
#pragma unroll
        for (int r = 0; r < 4; ++r) {
          const int row = m0 + wr * 64 + i * 16 + lg * 4 + r;
          C[(size_t)row * N + col] = f2bf(acc[i][j][r]);
        }
      }
  }
}

// ---------------- causal flash attention, swapped-QK^T ----------------------
// QKV: (MR,3072) bf16: [0,1024)=Q (pre-scaled 1/8), [1024,2048)=K, [2048,3072)=V
// grid: (32 bh, 32 y->qt). 4 waves/block, 16 q-rows/wave, KV tiles of 64.
// K in LDS: linear [64][64] with chunk-swizzle col8 ^= (row&7) (pre-swizzled src).
// V in LDS: [dc=4][kv=64][dl=16] (natural gld16 order), read via tr16.
__global__ __launch_bounds__(256, 4) void k_attn2(const u16* __restrict__ QKV,
                                                  u16* __restrict__ ctx) {
  __shared__ u16 Ks[2][64 * 64];
  __shared__ u16 Vs[2][64 * 64];

  const int t    = threadIdx.x;
  const int w    = t >> 6;
  const int l    = t & 63;
  const int ln15 = t & 15;
  const int lg   = (l >> 4) & 3;

  // balanced qt permutation: stride-8 sets {31-r,15-r,r,16+r} sum equal work
  const int by = blockIdx.y;
  const int r8 = by & 7, k4 = by >> 3;
  const int qt = (k4 == 0) ? (31 - r8) : (k4 == 1) ? (15 - r8)
               : (k4 == 2) ? r8 : (16 + r8);
  const int bh = blockIdx.x;
  const int b  = bh >> 4, h = bh & 15;

  const u16* KVb = QKV + (size_t)b * S_LEN * E3 + h * HD;
  const u16* Kg  = KVb + 1024;
  const u16* Vg  = KVb + 2048;
  const int qrow = qt * 64 + w * 16;

  // Q fragments (B-operand): lane (ln15,lg): Q[qrow+ln15][32*sd + 8*lg ..+7]
  short8_t qf[2];
  {
    const u16* qp = KVb + (size_t)(qrow + ln15) * E3 + 8 * lg;
    qf[0] = *reinterpret_cast<const short8_t*>(qp);
    qf[1] = *reinterpret_cast<const short8_t*>(qp + 32);
  }

  // staging address components
  const int krow_lo = l >> 3;                    // row&7 of K stage row
  const int kcol    = 8 * ((l & 7) ^ krow_lo);   // pre-swizzled source col
  const int vkv     = l >> 1;                    // 0..31
  const int vcol    = 16 * w + 8 * (l & 1);      // dc=w chunk

  // K-frag read offsets (swizzled): chunk XOR with ln15&7
  const int kx  = 8 * (ln15 & 7);
  const int kc0 = (8 * lg) ^ kx;         // sd=0
  const int kc1 = (32 + 8 * lg) ^ kx;    // sd=1

#define STAGE(buf, kv0)                                                        \
  do {                                                                         \
    gld16(Kg + (size_t)((kv0) + 16 * w + krow_lo) * E3 + kcol,                 \
          &Ks[buf][1024 * w]);                                                 \
    gld16(Kg + (size_t)((kv0) + 16 * w + 8 + krow_lo) * E3 + kcol,             \
          &Ks[buf][1024 * w + 512]);                                           \
    gld16(Vg + (size_t)((kv0) + vkv) * E3 + vcol, &Vs[buf][1024 * w]);         \
    gld16(Vg + (size_t)((kv0) + 32 + vkv) * E3 + vcol,                         \
          &Vs[buf][1024 * w + 512]);                                           \
  } while (0)

  f32x4_t o[4] = {};
  float mrow = -3e38f, lrow = 0.0f;
  const int nt_tiles = qt + 1;

  STAGE(0, 0);
  int cur = 0;

  for (int kvt = 0; kvt < nt_tiles; ++kvt) {
    const int kv0 = kvt * 64;
    asm volatile("s_barrier" ::: "memory");  // all waves done reading buf[cur^1]
    if (kvt + 1 < nt_tiles) {
      STAGE(cur ^ 1, kv0 + 64);
      asm volatile("s_waitcnt vmcnt(4)" ::: "memory");
    } else {
      asm volatile("s_waitcnt vmcnt(0)" ::: "memory");
    }
    asm volatile("s_barrier" ::: "memory");  // buf[cur] ready for all waves

    // ---- issue V tr-reads early (latency hides under QK^T + softmax) ----
    // FIX (r2->r3): canonical tr-read base = elem 4*l (byte 8*l), NOT
    // ln15+64*lg. Per 16-lane group transposes its 128B chunk:
    // elem j of half h = V[kv0 + 32*s2 + 16*h + 4*lg + j][16*nt + ln15].
    const __attribute__((address_space(3))) u16* vp =
        (const __attribute__((address_space(3))) u16*)&Vs[cur][4 * l];
    s4v vf[4][2][2];
#pragma unroll
    for (int nt = 0; nt < 4; ++nt) {
      // OFF bytes = 2048*nt + 1024*s2 + 512*h
      if (nt == 0) { vf[0][0][0]=tr16<0>(vp);    vf[0][0][1]=tr16<512>(vp);
                     vf[0][1][0]=tr16<1024>(vp); vf[0][1][1]=tr16<1536>(vp); }
      if (nt == 1) { vf[1][0][0]=tr16<2048>(vp); vf[1][0][1]=tr16<2560>(vp);
                     vf[1][1][0]=tr16<3072>(vp); vf[1][1][1]=tr16<3584>(vp); }
      if (nt == 2) { vf[2][0][0]=tr16<4096>(vp); vf[2][0][1]=tr16<4608>(vp);
                     vf[2][1][0]=tr16<5120>(vp); vf[2][1][1]=tr16<5632>(vp); }
      if (nt == 3) { vf[3][0][0]=tr16<6144>(vp); vf[3][0][1]=tr16<6656>(vp);
                     vf[3][1][0]=tr16<7168>(vp); vf[3][1][1]=tr16<7680>(vp); }
    }

    // ---- S^T = mfma(K, Q): lane holds S[q=qrow+ln15][kv=kv0+16ks+4lg+r] ----
    f32x4_t tacc[4];
#pragma unroll
    for (int ks = 0; ks < 4; ++ks) {
      const int R = 16 * ks + ln15;
      short8_t kf0 = *reinterpret_cast<const short8_t*>(&Ks[cur][R * 64 + kc0]);
      short8_t kf1 = *reinterpret_cast<const short8_t*>(&Ks[cur][R * 64 + kc1]);
      f32x4_t a = {0.f, 0.f, 0.f, 0.f};
      a = __builtin_amdgcn_mfma_f32_16x16x32_bf16(kf0, qf[0], a, 0, 0, 0);
      a = __builtin_amdgcn_mfma_f32_16x16x32_bf16(kf1, qf[1], a, 0, 0, 0);
      tacc[ks] = a;
    }

    // ---- causal mask (diagonal tile only) ----
    if (kvt == qt) {
      const int qg = qrow + ln15;
#pragma unroll
      for (int ks = 0; ks < 4; ++ks)
#pragma unroll
        for (int r = 0; r < 4; ++r)
          if (kv0 + 16 * ks + 4 * lg + r > qg) tacc[ks][r] = -3e38f;
    }

    // ---- online softmax: lane owns 16 of row q=ln15's values ----
    float rm = -3e38f;
#pragma unroll
    for (int ks = 0; ks < 4; ++ks)
#pragma unroll
      for (int r = 0; r < 4; ++r) rm = fmaxf(rm, tacc[ks][r]);
    rm = fmaxf(rm, __shfl_xor(rm, 16, 64));
    rm = fmaxf(rm, __shfl_xor(rm, 32, 64));
    const float nm = fmaxf(mrow, rm);
    const float sc_old = exp2f((mrow - nm) * L2E);
    mrow = nm;

    float p[4][4];
    float rs = 0.0f;
#pragma unroll
    for (int ks = 0; ks < 4; ++ks)
#pragma unroll
      for (int r = 0; r < 4; ++r) {
        const float pv = exp2f((tacc[ks][r] - nm) * L2E);
        p[ks][r] = pv;
        rs += pv;
      }
    rs += __shfl_xor(rs, 16, 64);
    rs += __shfl_xor(rs, 32, 64);
    lrow = lrow * sc_old + rs;

    // rescale o (o rows are q=4lg+r; fetch sc_old from lane ln15=4lg+r)
#pragma unroll
    for (int r = 0; r < 4; ++r) {
      const float so = __shfl(sc_old, 20 * lg + r, 64);
#pragma unroll
      for (int nt = 0; nt < 4; ++nt) o[nt][r] *= so;
    }

    // ---- P is already the PV A-operand in-register ----
    short8_t pf[2];
#pragma unroll
    for (int s2 = 0; s2 < 2; ++s2)
#pragma unroll
      for (int j = 0; j < 4; ++j) {
        pf[s2][j]     = (short)f2bf(p[2 * s2][j]);
        pf[s2][j + 4] = (short)f2bf(p[2 * s2 + 1][j]);
      }

    asm volatile("s_waitcnt lgkmcnt(0)");
    __builtin_amdgcn_sched_barrier(0);

#pragma unroll
    for (int nt = 0; nt < 4; ++nt) {
#pragma unroll
      for (int s2 = 0; s2 < 2; ++s2) {
        short8_t bv = __builtin_shufflevector(vf[nt][s2][0], vf[nt][s2][1],
                                              0, 1, 2, 3, 4, 5, 6, 7);
        o[nt] = __builtin_amdgcn_mfma_f32_16x16x32_bf16(pf[s2], bv, o[nt], 0, 0, 0);
      }
    }
    cur ^= 1;
  }
#undef STAGE

  // ---- epilogue: normalize and write ctx ----
  const float linv = 1.0f / lrow;
#pragma unroll
  for (int r = 0; r < 4; ++r) {
    const float li = __shfl(linv, 20 * lg + r, 64);
    u16* op = ctx + (size_t)(b * S_LEN + qrow + 4 * lg + r) * EMB + h * HD;
#pragma unroll
    for (int nt = 0; nt < 4; ++nt)
      op[nt * 16 + ln15] = f2bf(o[nt][r] * li);
  }
}

// ---------------------------------------------------------------------------
extern "C" void kernel_launch(void* const* d_in, const int* in_sizes, int n_in,
                              void* d_out, int out_size, void* d_ws, size_t ws_size,
                              hipStream_t stream) {
  const float* x  = (const float*)d_in[0];
  const float* Wq = (const float*)d_in[1];
  const float* Wk = (const float*)d_in[2];
  const float* Wv = (const float*)d_in[3];
  const float* Wo = (const float*)d_in[4];
  const float* bo = (const float*)d_in[5];

  u16* ws   = (u16*)d_ws;
  u16* xb   = ws;                               // 4096*1024
  u16* wcat = xb + (size_t)MR * EMB;            // 3*1024*1024 (Wq|Wk|Wv rows)
  u16* wob  = wcat + (size_t)3 * EMB * EMB;     // 1024*1024
  u16* qkv  = wob + (size_t)EMB * EMB;          // 4096*3072
  u16* ctxb = qkv + (size_t)MR * E3;            // 4096*1024

  // fused fp32 -> bf16 (x | Wq*0.125 | Wk | Wv | Wo), dest contiguous at xb
  k_cvt_all<<<8192, 256, 0, stream>>>(x, Wq, Wk, Wv, Wo, xb);

  // QKV = x @ Wcat^T  (M=4096, N=3072, K=1024), bf16 out
  k_gemm_bt<false><<<dim3(E3 / 128, MR / 128), 256, 0, stream>>>(
      xb, wcat, qkv, nullptr, MR, E3, EMB);

  // causal flash attention -> ctx (bf16)
  k_attn2<<<dim3(BATCH * NH, 32), 256, 0, stream>>>(qkv, ctxb);

  // out = ctx @ Wo^T + bo  (fp32 out)
  k_gemm_bt<true><<<dim3(EMB / 128, MR / 128), 256, 0, stream>>>(
      ctxb, wob, d_out, bo, MR, EMB, EMB);
}

// Round 5
// 127.757 us; speedup vs baseline: 1.9533x; 1.0008x over previous
//
#include <hip/hip_runtime.h>
#include <hip/hip_bf16.h>

typedef __attribute__((ext_vector_type(8))) short short8_t;
typedef __attribute__((ext_vector_type(4))) short s4v;
typedef __attribute__((ext_vector_type(4))) float f32x4_t;
using u16 = unsigned short;

constexpr int S_LEN = 2048;
constexpr int EMB   = 1024;
constexpr int NH    = 16;
constexpr int HD    = 64;
constexpr int BATCH = 2;
constexpr int MR    = BATCH * S_LEN;  // 4096
constexpr int E3    = 3 * EMB;        // 3072

#define L2E 1.44269504f

__device__ __forceinline__ u16 f2bf(float f) {
  unsigned u = __builtin_bit_cast(unsigned, f);
  unsigned r = 0x7fffu + ((u >> 16) & 1u);
  return (u16)((u + r) >> 16);
}

__device__ __forceinline__ void gld16(const void* g, void* l) {
  __builtin_amdgcn_global_load_lds(
      (const __attribute__((address_space(1))) void*)g,
      (__attribute__((address_space(3))) void*)l, 16, 0, 0);
}

// hardware transpose read. Canonical per-lane address = base + 8B*lane:
// lane l, elem j <- lds_elem[64*(l>>4) + 16*j + (l&15)] (+ offset/2 elems).
template <int OFF>
__device__ __forceinline__ s4v tr16(const __attribute__((address_space(3))) u16* p) {
  s4v d;
  asm volatile("ds_read_b64_tr_b16 %0, %1 offset:%2"
               : "=v"(d) : "v"(p), "n"(OFF));
  return d;
}

// ---------------- fused fp32 -> bf16 conversion ----------------------------
// dest layout (contiguous in ws): xb(4M) | Wq(1M,*0.125) | Wk | Wv | Wo
__global__ void k_cvt_all(const float* __restrict__ x, const float* __restrict__ Wq,
                          const float* __restrict__ Wk, const float* __restrict__ Wv,
                          const float* __restrict__ Wo, u16* __restrict__ out) {
  int i = blockIdx.x * 256 + threadIdx.x;  // float4 index, total 2M
  const float* src;
  int j;
  float sc = 1.0f;
  if (i < (1 << 20)) {
    src = x; j = i;
  } else {
    int jj = i - (1 << 20);
    int r = jj >> 18;
    j = jj & ((1 << 18) - 1);
    src = (r == 0) ? Wq : (r == 1) ? Wk : (r == 2) ? Wv : Wo;
    if (r == 0) sc = 0.125f;  // fold softmax 1/sqrt(64)
  }
  float4 v = reinterpret_cast<const float4*>(src)[j];
  ushort4 o;
  o.x = f2bf(v.x * sc); o.y = f2bf(v.y * sc);
  o.z = f2bf(v.z * sc); o.w = f2bf(v.w * sc);
  reinterpret_cast<ushort4*>(out)[i] = o;
}

// ---------------- bf16 GEMM, B^T input (C = A @ B^T), 128x128 tile ---------
template <bool F32OUT>
__global__ __launch_bounds__(256) void k_gemm_bt(
    const u16* __restrict__ A, const u16* __restrict__ Bw,
    void* __restrict__ Cv, const float* __restrict__ bias,
    int M, int N, int K) {
  __shared__ short As[128 * 32];
  __shared__ short Bs[128 * 32];
  const int t    = threadIdx.x;
  const int w    = t >> 6;
  const int ln15 = t & 15;
  const int lg   = (t >> 4) & 3;
  const int wr   = w >> 1, wc = w & 1;
  const int m0   = blockIdx.y * 128, n0 = blockIdx.x * 128;

  const int srow = t >> 2;
  const int scol = (t & 3) * 8;
  const u16* gA = A + (size_t)(m0 + srow) * K + scol;
  const u16* gB = Bw + (size_t)(n0 + srow) * K + scol;
  short* lA = As + w * 512;
  short* lB = Bs + w * 512;

  f32x4_t acc[4][4] = {};

  for (int k0 = 0; k0 < K; k0 += 32) {
    gld16(gA + k0, lA);
    gld16(gA + (size_t)64 * K + k0, lA + 2048);
    gld16(gB + k0, lB);
    gld16(gB + (size_t)64 * K + k0, lB + 2048);
    __syncthreads();
    short8_t af[4], bf[4];
#pragma unroll
    for (int i = 0; i < 4; ++i) {
      af[i] = *reinterpret_cast<const short8_t*>(
          &As[(wr * 64 + i * 16 + ln15) * 32 + 8 * lg]);
      bf[i] = *reinterpret_cast<const short8_t*>(
          &Bs[(wc * 64 + i * 16 + ln15) * 32 + 8 * lg]);
    }
#pragma unroll
    for (int i = 0; i < 4; ++i)
#pragma unroll
      for (int j = 0; j < 4; ++j)
        acc[i][j] = __builtin_amdgcn_mfma_f32_16x16x32_bf16(
            af[i], bf[j], acc[i][j], 0, 0, 0);
    __syncthreads();
  }

  if (F32OUT) {
    float* C = reinterpret_cast<float*>(Cv);
#pragma unroll
    for (int i = 0; i < 4; ++i)
#pragma unroll
      for (int j = 0; j < 4; ++j) {
        const int col = n0 + wc * 64 + j * 16 + ln15;
        const float bv = bias ? bias[col] : 0.0f;
#pragma unroll
        for (int r = 0; r < 4; ++r) {
          const int row = m0 + wr * 64 + i * 16 + lg * 4 + r;
          C[(size_t)row * N + col] = acc[i][j][r] + bv;
        }
      }
  } else {
    u16* C = reinterpret_cast<u16*>(Cv);
#pragma unroll
    for (int i = 0; i < 4; ++i)
#pragma unroll
      for (int j = 0; j < 4; ++j) {
        const int col = n0 + wc * 64 + j * 16 + ln15;
#pragma unroll
        for (int r = 0; r < 4; ++r) {
          const int row = m0 + wr * 64 + i * 16 + lg * 4 + r;
          C[(size_t)row * N + col] = f2bf(acc[i][j][r]);
        }
      }
  }
}

// ---------------- causal flash attention, swapped-QK^T ----------------------
// QKV: (MR,3072) bf16: [0,1024)=Q (pre-scaled 1/8), [1024,2048)=K, [2048,3072)=V
// grid: (32 bh, 32 y->qt, LPT heavy-first). 4 waves/block, 16 q-rows/wave.
// K in LDS: linear [64][64] with chunk-swizzle col8 ^= (row&7) (pre-swizzled src).
// V in LDS: [dc=4][kv=64][dl=16] (natural gld16 order), read via tr16.
__global__ __launch_bounds__(256, 4) void k_attn2(const u16* __restrict__ QKV,
                                                  u16* __restrict__ ctx) {
  __shared__ u16 Ks[2][64 * 64];
  __shared__ u16 Vs[2][64 * 64];

  const int t    = threadIdx.x;
  const int w    = t >> 6;
  const int l    = t & 63;
  const int ln15 = t & 15;
  const int lg   = (l >> 4) & 3;

  // LPT: heaviest qt dispatched first, light blocks fill the tail
  const int qt = 31 - blockIdx.y;
  const int bh = blockIdx.x;
  const int b  = bh >> 4, h = bh & 15;

  const u16* KVb = QKV + (size_t)b * S_LEN * E3 + h * HD;
  const u16* Kg  = KVb + 1024;
  const u16* Vg  = KVb + 2048;
  const int qrow = qt * 64 + w * 16;

  // Q fragments (B-operand): lane (ln15,lg): Q[qrow+ln15][32*sd + 8*lg ..+7]
  short8_t qf[2];
  {
    const u16* qp = KVb + (size_t)(qrow + ln15) * E3 + 8 * lg;
    qf[0] = *reinterpret_cast<const short8_t*>(qp);
    qf[1] = *reinterpret_cast<const short8_t*>(qp + 32);
  }

  // staging address components
  const int krow_lo = l >> 3;                    // row&7 of K stage row
  const int kcol    = 8 * ((l & 7) ^ krow_lo);   // pre-swizzled source col
  const int vkv     = l >> 1;                    // 0..31
  const int vcol    = 16 * w + 8 * (l & 1);      // dc=w chunk

  // K-frag read offsets (swizzled): chunk XOR with ln15&7
  const int kx  = 8 * (ln15 & 7);
  const int kc0 = (8 * lg) ^ kx;         // sd=0
  const int kc1 = (32 + 8 * lg) ^ kx;    // sd=1

#define STAGE(buf, kv0)                                                        \
  do {                                                                         \
    gld16(Kg + (size_t)((kv0) + 16 * w + krow_lo) * E3 + kcol,                 \
          &Ks[buf][1024 * w]);                                                 \
    gld16(Kg + (size_t)((kv0) + 16 * w + 8 + krow_lo) * E3 + kcol,             \
          &Ks[buf][1024 * w + 512]);                                           \
    gld16(Vg + (size_t)((kv0) + vkv) * E3 + vcol, &Vs[buf][1024 * w]);         \
    gld16(Vg + (size_t)((kv0) + 32 + vkv) * E3 + vcol,                         \
          &Vs[buf][1024 * w + 512]);                                           \
  } while (0)

  f32x4_t o[4] = {};
  float mrow = -3e38f, lrow = 0.0f;
  const int nt_tiles = qt + 1;

  STAGE(0, 0);
  int cur = 0;

  for (int kvt = 0; kvt < nt_tiles; ++kvt) {
    const int kv0 = kvt * 64;
    asm volatile("s_barrier" ::: "memory");  // all waves done reading buf[cur^1]
    if (kvt + 1 < nt_tiles) {
      STAGE(cur ^ 1, kv0 + 64);
      asm volatile("s_waitcnt vmcnt(4)" ::: "memory");
    } else {
      asm volatile("s_waitcnt vmcnt(0)" ::: "memory");
    }
    asm volatile("s_barrier" ::: "memory");  // buf[cur] ready for all waves

    // ---- issue V tr-reads early (latency hides under QK^T + softmax) ----
    // elem j of half h = V[kv0 + 32*s2 + 16*h + 4*lg + j][16*nt + ln15].
    const __attribute__((address_space(3))) u16* vp =
        (const __attribute__((address_space(3))) u16*)&Vs[cur][4 * l];
    s4v vf[4][2][2];
#pragma unroll
    for (int nt = 0; nt < 4; ++nt) {
      // OFF bytes = 2048*nt + 1024*s2 + 512*h
      if (nt == 0) { vf[0][0][0]=tr16<0>(vp);    vf[0][0][1]=tr16<512>(vp);
                     vf[0][1][0]=tr16<1024>(vp); vf[0][1][1]=tr16<1536>(vp); }
      if (nt == 1) { vf[1][0][0]=tr16<2048>(vp); vf[1][0][1]=tr16<2560>(vp);
                     vf[1][1][0]=tr16<3072>(vp); vf[1][1][1]=tr16<3584>(vp); }
      if (nt == 2) { vf[2][0][0]=tr16<4096>(vp); vf[2][0][1]=tr16<4608>(vp);
                     vf[2][1][0]=tr16<5120>(vp); vf[2][1][1]=tr16<5632>(vp); }
      if (nt == 3) { vf[3][0][0]=tr16<6144>(vp); vf[3][0][1]=tr16<6656>(vp);
                     vf[3][1][0]=tr16<7168>(vp); vf[3][1][1]=tr16<7680>(vp); }
    }

    // ---- S^T = mfma(K, Q): lane holds S[q=qrow+ln15][kv=kv0+16ks+4lg+r] ----
    f32x4_t tacc[4];
    __builtin_amdgcn_s_setprio(1);
#pragma unroll
    for (int ks = 0; ks < 4; ++ks) {
      const int R = 16 * ks + ln15;
      short8_t kf0 = *reinterpret_cast<const short8_t*>(&Ks[cur][R * 64 + kc0]);
      short8_t kf1 = *reinterpret_cast<const short8_t*>(&Ks[cur][R * 64 + kc1]);
      f32x4_t a = {0.f, 0.f, 0.f, 0.f};
      a = __builtin_amdgcn_mfma_f32_16x16x32_bf16(kf0, qf[0], a, 0, 0, 0);
      a = __builtin_amdgcn_mfma_f32_16x16x32_bf16(kf1, qf[1], a, 0, 0, 0);
      tacc[ks] = a;
    }
    __builtin_amdgcn_s_setprio(0);

    // ---- causal mask (diagonal tile only) ----
    if (kvt == qt) {
      const int qg = qrow + ln15;
#pragma unroll
      for (int ks = 0; ks < 4; ++ks)
#pragma unroll
        for (int r = 0; r < 4; ++r)
          if (kv0 + 16 * ks + 4 * lg + r > qg) tacc[ks][r] = -3e38f;
    }

    // ---- online softmax: lane owns 16 of row q=ln15's values ----
    float rm = fmaxf(
        fmaxf(fmaxf(fmaxf(tacc[0][0], tacc[0][1]), fmaxf(tacc[0][2], tacc[0][3])),
              fmaxf(fmaxf(tacc[1][0], tacc[1][1]), fmaxf(tacc[1][2], tacc[1][3]))),
        fmaxf(fmaxf(fmaxf(tacc[2][0], tacc[2][1]), fmaxf(tacc[2][2], tacc[2][3])),
              fmaxf(fmaxf(tacc[3][0], tacc[3][1]), fmaxf(tacc[3][2], tacc[3][3]))));
    rm = fmaxf(rm, __shfl_xor(rm, 16, 64));
    rm = fmaxf(rm, __shfl_xor(rm, 32, 64));

    // THR=0 exact-skip: when skipped, the rescale would have been *1.0 exactly
    if (__any(rm > mrow)) {
      const float nm = fmaxf(mrow, rm);
      const float sc = exp2f((mrow - nm) * L2E);
      mrow = nm;
      lrow *= sc;
#pragma unroll
      for (int r = 0; r < 4; ++r) {
        const float so = __shfl(sc, 20 * lg + r, 64);
#pragma unroll
        for (int nt = 0; nt < 4; ++nt) o[nt][r] *= so;
      }
    }

    const float nmL = mrow * L2E;
    float p[4][4];
    float rs = 0.0f;
#pragma unroll
    for (int ks = 0; ks < 4; ++ks)
#pragma unroll
      for (int r = 0; r < 4; ++r) {
        const float pv = exp2f(fmaf(tacc[ks][r], L2E, -nmL));
        p[ks][r] = pv;
        rs += pv;
      }
    rs += __shfl_xor(rs, 16, 64);
    rs += __shfl_xor(rs, 32, 64);
    lrow += rs;

    // ---- P pack (r3-verified bit-hack path) ----
    short8_t pf[2];
#pragma unroll
    for (int s2 = 0; s2 < 2; ++s2)
#pragma unroll
      for (int j = 0; j < 4; ++j) {
        pf[s2][j]     = (short)f2bf(p[2 * s2][j]);
        pf[s2][j + 4] = (short)f2bf(p[2 * s2 + 1][j]);
      }

    asm volatile("s_waitcnt lgkmcnt(0)");
    __builtin_amdgcn_sched_barrier(0);

    __builtin_amdgcn_s_setprio(1);
#pragma unroll
    for (int nt = 0; nt < 4; ++nt) {
#pragma unroll
      for (int s2 = 0; s2 < 2; ++s2) {
        short8_t bv = __builtin_shufflevector(vf[nt][s2][0], vf[nt][s2][1],
                                              0, 1, 2, 3, 4, 5, 6, 7);
        o[nt] = __builtin_amdgcn_mfma_f32_16x16x32_bf16(pf[s2], bv, o[nt], 0, 0, 0);
      }
    }
    __builtin_amdgcn_s_setprio(0);
    cur ^= 1;
  }
#undef STAGE

  // ---- epilogue: normalize and write ctx ----
  const float linv = 1.0f / lrow;
#pragma unroll
  for (int r = 0; r < 4; ++r) {
    const float li = __shfl(linv, 20 * lg + r, 64);
    u16* op = ctx + (size_t)(b * S_LEN + qrow + 4 * lg + r) * EMB + h * HD;
#pragma unroll
    for (int nt = 0; nt < 4; ++nt)
      op[nt * 16 + ln15] = f2bf(o[nt][r] * li);
  }
}

// ---------------------------------------------------------------------------
extern "C" void kernel_launch(void* const* d_in, const int* in_sizes, int n_in,
                              void* d_out, int out_size, void* d_ws, size_t ws_size,
                              hipStream_t stream) {
  const float* x  = (const float*)d_in[0];
  const float* Wq = (const float*)d_in[1];
  const float* Wk = (const float*)d_in[2];
  const float* Wv = (const float*)d_in[3];
  const float* Wo = (const float*)d_in[4];
  const float* bo = (const float*)d_in[5];

  u16* ws   = (u16*)d_ws;
  u16* xb   = ws;                               // 4096*1024
  u16* wcat = xb + (size_t)MR * EMB;            // 3*1024*1024 (Wq|Wk|Wv rows)
  u16* wob  = wcat + (size_t)3 * EMB * EMB;     // 1024*1024
  u16* qkv  = wob + (size_t)EMB * EMB;          // 4096*3072
  u16* ctxb = qkv + (size_t)MR * E3;            // 4096*1024

  // fused fp32 -> bf16 (x | Wq*0.125 | Wk | Wv | Wo), dest contiguous at xb
  k_cvt_all<<<8192, 256, 0, stream>>>(x, Wq, Wk, Wv, Wo, xb);

  // QKV = x @ Wcat^T  (M=4096, N=3072, K=1024), bf16 out
  k_gemm_bt<false><<<dim3(E3 / 128, MR / 128), 256, 0, stream>>>(
      xb, wcat, qkv, nullptr, MR, E3, EMB);

  // causal flash attention -> ctx (bf16)
  k_attn2<<<dim3(BATCH * NH, 32), 256, 0, stream>>>(qkv, ctxb);

  // out = ctx @ Wo^T + bo  (fp32 out)
  k_gemm_bt<true><<<dim3(EMB / 128, MR / 128), 256, 0, stream>>>(
      ctxb, wob, d_out, bo, MR, EMB, EMB);
}